// Round 7
// baseline (290.277 us; speedup 1.0000x reference)
//
#include <hip/hip_runtime.h>
#include <math.h>

#define D_IN 128
#define HC 100
#define PW 128          // padded hs row width (ushorts); rows 256B-aligned.
#define CAP 64          // per-dst bucket capacity; P(Poisson(16) > 64) ~ 1e-19
#define NEG 0.2f
#define BINSH 6         // bin = dst >> 6 (64 nodes/bin, 1563 bins for N=100000)
#define NBIN 1563
#define BCAP 1408       // per-bin edge capacity (avg 1024, +12 sigma)
#define ACH 4096        // edges per binA block
#define YSLOT 32        // ypart slots per batch; slot=blk&31 -> XCD-private lines
#define SRCM 0x1FFFF    // 17-bit src mask in packed ebuf entry

typedef __attribute__((ext_vector_type(8))) short short8;
typedef __attribute__((ext_vector_type(4))) float f32x4;
typedef __attribute__((ext_vector_type(2))) float f32x2;

__device__ __forceinline__ float lrelu(float x){ return x > 0.f ? x : NEG*x; }

__device__ __forceinline__ unsigned short f2bf(float f){
  union { float f; unsigned u; } v; v.f = f;
  unsigned r = v.u + 0x7fffu + ((v.u >> 16) & 1u);   // RNE
  return (unsigned short)(r >> 16);
}
__device__ __forceinline__ float bflo(unsigned u){
  union { unsigned x; float f; } v; v.x = u << 16; return v.f;
}
__device__ __forceinline__ float bfhi(unsigned u){
  union { unsigned x; float f; } v; v.x = u & 0xffff0000u; return v.f;
}

// block 0: wv = W_dst . att_dst; padded bias/fcw tables; y[b] = fcb; invb;
//          zero bincnt.  block 1: pack W_src into MFMA B-fragment order.
// blocks 2,3: zero ypart.
__global__ __launch_bounds__(256) void k_init(const float* __restrict__ Wd,
    const float* __restrict__ attd, const float* __restrict__ Ws,
    const float* __restrict__ bias, const float* __restrict__ fcw,
    const float* __restrict__ fcb, const int* __restrict__ xsb,
    float* __restrict__ wv, float* __restrict__ bias_p, float* __restrict__ fcwp,
    unsigned short* __restrict__ Wp, float* __restrict__ invb,
    int* __restrict__ bincnt, float* __restrict__ ypart,
    float* __restrict__ y, int N, int B){
  __shared__ int lo[257];
  int t = threadIdx.x;
  if (blockIdx.x == 0){
    int h = t >> 7, k = t & 127;
    float s = 0.f;
    #pragma unroll
    for (int c = 0; c < 50; ++c) s += Wd[k*HC + h*50 + c] * attd[h*50 + c];
    wv[t] = s;
    if (t < 128){
      bool cv = (t < 50) || (t >= 56 && t < 106);
      int c = (t < 50) ? t : t - 6;
      bias_p[t] = cv ? bias[c] : 0.f;
      fcwp[t]   = cv ? fcw[c]  : 0.f;
    }
    if (t < B) y[t] = fcb[0];
    for (int i = t; i < NBIN; i += 256) bincnt[i] = 0;
    if (t <= B && t < 257){
      int key = t, l = 0, hi = N;
      while (l < hi){ int mid = (l+hi)>>1; if (xsb[mid] < key) l = mid+1; else hi = mid; }
      lo[t] = l;
    }
    __syncthreads();
    if (t < B){
      int c = lo[t+1] - lo[t];
      invb[t] = 1.f / (float)((c > 0) ? c : 1);
    }
  } else if (blockIdx.x == 1){
    for (int idx = t; idx < 1792; idx += 256){
      int ct = idx >> 8, kk = (idx >> 6) & 3, lane = idx & 63;
      int kb = kk*32 + (lane >> 4)*8;
      int c  = ct*16 + (lane & 15);
      #pragma unroll
      for (int j = 0; j < 8; ++j){
        float v = (c < HC) ? Ws[(size_t)(kb + j)*HC + c] : 0.f;
        Wp[idx*8 + j] = f2bf(v);
      }
    }
  } else {
    // zero ypart: B*YSLOT*32 floats = 65536 -> 8192 float4 per block
    float4 z = make_float4(0.f,0.f,0.f,0.f);
    float4* yp4 = (float4*)ypart + (size_t)(blockIdx.x - 2)*8192;
    for (int i = t; i < 8192; i += 256) yp4[i] = z;
  }
}

// Grid-partitioned fused kernel: [0,Gb) binA+a_dst FIRST (atomic- and
// stream-latency work overlaps the gemm bulk) | [Gb,..) gemm (x_s only).
__global__ __launch_bounds__(256) void k_fused(
    const float* __restrict__ x_s, const unsigned short* __restrict__ Wp,
    const float* __restrict__ atts, unsigned short* __restrict__ hsb,
    float* __restrict__ a_src,
    const float* __restrict__ x_t, const float* __restrict__ wv,
    float* __restrict__ a_dst,
    const int* __restrict__ ei, int* __restrict__ bincnt,
    int* __restrict__ ebuf,
    int N, int E, int Gb)
{
  __shared__ __align__(16) unsigned char smem[17408];
  int t = threadIdx.x;
  int bid = blockIdx.x;

  if (bid >= Gb){
    // ---- MFMA bf16 GEMM: hs = x_s @ W_src + fused a_src (no x_t here) ----
    unsigned short* hls = (unsigned short*)smem;      // 64*PW ushorts = 16384 B
    int lane = t & 63, w = t >> 6;
    int qr = lane & 15, qq = lane >> 4;
    int row0 = (bid - Gb)*64;

    for (int i = t; i < 4096; i += 256) ((unsigned*)hls)[i] = 0u;

    int arow = row0 + w*16 + qr;
    bool rv = arow < N;
    short8 afr[4];
    const float* xp = x_s + (size_t)arow*D_IN + qq*8;
    #pragma unroll
    for (int kk = 0; kk < 4; ++kk){
      float4 v0 = make_float4(0.f,0.f,0.f,0.f), v1 = v0;
      if (rv){ v0 = *(const float4*)(xp + kk*32); v1 = *(const float4*)(xp + kk*32 + 4); }
      short8 a;
      a[0]=(short)f2bf(v0.x); a[1]=(short)f2bf(v0.y); a[2]=(short)f2bf(v0.z); a[3]=(short)f2bf(v0.w);
      a[4]=(short)f2bf(v1.x); a[5]=(short)f2bf(v1.y); a[6]=(short)f2bf(v1.z); a[7]=(short)f2bf(v1.w);
      afr[kk] = a;
    }

    f32x4 acc[7];
    #pragma unroll
    for (int ct = 0; ct < 7; ++ct) acc[ct] = (f32x4){0.f,0.f,0.f,0.f};
    #pragma unroll
    for (int kk = 0; kk < 4; ++kk){
      #pragma unroll
      for (int ct = 0; ct < 7; ++ct){
        short8 b = *(const short8*)&Wp[(size_t)((ct*4+kk)*64 + lane)*8];
        acc[ct] = __builtin_amdgcn_mfma_f32_16x16x32_bf16(afr[kk], b, acc[ct], 0, 0, 0);
      }
    }

    float p0[4] = {0,0,0,0}, p1[4] = {0,0,0,0};
    #pragma unroll
    for (int ct = 0; ct < 7; ++ct){
      int c = ct*16 + qr;
      if (c < HC){
        float av = atts[c];
        #pragma unroll
        for (int r = 0; r < 4; ++r){
          float v = acc[ct][r];
          if (c < 50) p0[r] += v*av; else p1[r] += v*av;
        }
      }
    }
    #pragma unroll
    for (int d = 1; d < 16; d <<= 1){
      #pragma unroll
      for (int r = 0; r < 4; ++r){
        p0[r] += __shfl_xor(p0[r], d, 64);
        p1[r] += __shfl_xor(p1[r], d, 64);
      }
    }
    if (qr == 0){
      #pragma unroll
      for (int r = 0; r < 4; ++r){
        int row = row0 + w*16 + qq*4 + r;
        if (row < N){ a_src[row*2] = p0[r]; a_src[row*2+1] = p1[r]; }
      }
    }

    __syncthreads();   // hls zero complete before value writes
    #pragma unroll
    for (int ct = 0; ct < 7; ++ct){
      int c = ct*16 + qr;
      if (c < HC){
        int p = (c < 50) ? c : c + 6;
        #pragma unroll
        for (int r = 0; r < 4; ++r)
          hls[(w*16 + qq*4 + r)*PW + p] = f2bf(acc[ct][r]);
      }
    }
    __syncthreads();
    unsigned* hg = (unsigned*)(hsb + (size_t)row0*PW);
    for (int i = t; i < 4096; i += 256) hg[i] = ((unsigned*)hls)[i];

  } else {
    // ---- binA: bin edges by dst>>BINSH (LDS rank + one reserve-atomic/bin,
    //      packed entry src|ld<<17) THEN a_dst for rows [bid*256, +256):
    //      stream+shfl work fills this branch's idle issue slots.
    int* cnt   = (int*)smem;                      // [NBIN]
    int* gbase = (int*)smem + NBIN;               // [NBIN]
    float* wsh = (float*)(smem + 12544);          // 256 floats (aligned)
    int e0 = bid * ACH;
    wsh[t] = wv[t];
    for (int i = t; i < NBIN; i += 256) cnt[i] = 0;
    __syncthreads();

    int src[16], dst[16], rank[16];
    #pragma unroll
    for (int j = 0; j < 4; ++j){
      int e = e0 + t*16 + j*4;
      bool in = (e + 4 <= E);                 // E % 4 == 0: chunks fully in or out
      int4 s4 = in ? *(const int4*)&ei[e]     : make_int4(0,0,0,0);
      int4 d4 = in ? *(const int4*)&ei[E + e] : make_int4(-1,-1,-1,-1);
      src[j*4+0]=s4.x; src[j*4+1]=s4.y; src[j*4+2]=s4.z; src[j*4+3]=s4.w;
      dst[j*4+0]=d4.x; dst[j*4+1]=d4.y; dst[j*4+2]=d4.z; dst[j*4+3]=d4.w;
    }
    #pragma unroll
    for (int j = 0; j < 16; ++j)
      rank[j] = (dst[j] >= 0) ? atomicAdd(&cnt[dst[j] >> BINSH], 1) : -1;
    __syncthreads();
    for (int i = t; i < NBIN; i += 256)
      gbase[i] = (cnt[i] > 0) ? atomicAdd(&bincnt[i], cnt[i]) : 0;
    __syncthreads();
    #pragma unroll
    for (int j = 0; j < 16; ++j){
      if (rank[j] >= 0){
        int b = dst[j] >> BINSH;
        int gp = gbase[b] + rank[j];
        if (gp < BCAP) ebuf[(size_t)b*BCAP + gp] = src[j] | ((dst[j] & 63) << 17);
      }
    }

    // a_dst phase: 4 waves x 64 rows, one coalesced row per iteration.
    int lane = t & 63, w = t >> 6;
    int rbase = bid*256 + w*64;
    float w0a = wsh[lane*2],     w0b = wsh[lane*2+1];
    float w1a = wsh[128+lane*2], w1b = wsh[128+lane*2+1];
    #pragma unroll 2
    for (int rr = 0; rr < 64; ++rr){
      int row = rbase + rr;
      if (row >= N) break;               // wave-uniform
      float2 x2 = *(const float2*)&x_t[(size_t)row*D_IN + lane*2];
      float p0 = x2.x*w0a + x2.y*w0b;
      float p1 = x2.x*w1a + x2.y*w1b;
      #pragma unroll
      for (int d = 32; d >= 1; d >>= 1){
        p0 += __shfl_xor(p0, d, 64); p1 += __shfl_xor(p1, d, 64);
      }
      if (lane == 0){ a_dst[row*2] = p0; a_dst[row*2+1] = p1; }
    }
  }
}

// Merged binB + agg: block b owns HALF-bin b (32 nodes, 128 threads).
// Phase 1 filters/groups the bin's packed edges into an LDS bucket table;
// phase 2: 2 waves x 16 nodes each run the per-node flow. Softmax WITHOUT
// max-subtraction: exp(e)/sum(exp(e)) is mathematically identical and logits
// are bounded (|e| <~ 20 for this model; clamp 60 guards overflow) -> removes
// the entire 14-op max butterfly chain per node.
__global__ __launch_bounds__(128) void k_agg(const int* __restrict__ bincnt,
    const int* __restrict__ ebuf, const float* __restrict__ a_src,
    const float* __restrict__ a_dst, const unsigned short* __restrict__ hsb,
    const float* __restrict__ bias_p, const float* __restrict__ fcwp,
    const int* __restrict__ xsb, float* __restrict__ ypart, int N)
{
  __shared__ int lsrc[32*CAP];    // 8192 B
  __shared__ int lcnt[32];
  int t = threadIdx.x, b = blockIdx.x;
  int bin = b >> 1, half = b & 1;
  if (t < 32) lcnt[t] = 0;
  __syncthreads();
  int nE = bincnt[bin]; if (nE > BCAP) nE = BCAP;
  const int* eb = ebuf + (size_t)bin*BCAP;
  for (int i = t; i < nE; i += 128){
    int e = eb[i];
    int ld = (e >> 17) & 63;
    if ((ld >> 5) == half){
      int p = atomicAdd(&lcnt[ld & 31], 1);
      if (p < CAP) lsrc[(ld & 31)*CAP + p] = e & SRCM;
    }
  }
  __syncthreads();

  int lane = t & 63, w = t >> 6;
  int k = lane & 15, g = lane >> 4;
  bool actv = (k < 14);
  bool hsel = (k >= 7);

#define PREF(vv, e) { int s_ = __shfl(sreg, (e), 64); \
    vv = (actv && (e) < deg) ? *(const uint4*)&hsb[(size_t)s_*PW + k*8] \
                             : make_uint4(0u,0u,0u,0u); }

#define CONS(vv, e) { float a0_ = __shfl(al0, (e), 64); float a1_ = __shfl(al1, (e), 64); \
    float a_ = hsel ? a1_ : a0_; f32x2 av_ = {a_, a_}; \
    f32x2 h0_ = {bflo(vv.x), bfhi(vv.x)}; acc0 += av_*h0_; \
    f32x2 h1_ = {bflo(vv.y), bfhi(vv.y)}; acc1 += av_*h1_; \
    f32x2 h2_ = {bflo(vv.z), bfhi(vv.z)}; acc2 += av_*h2_; \
    f32x2 h3_ = {bflo(vv.w), bfhi(vv.w)}; acc3 += av_*h3_; }

  for (int it = 0; it < 16; ++it){
    int nl = w*16 + it;
    int n  = bin*64 + half*32 + nl;
    if (n >= N) break;                 // wave-uniform; no barriers below
    int deg = lcnt[nl]; if (deg > CAP) deg = CAP;
    float2 ad = *(const float2*)&a_dst[n*2];
    int sreg = (lane < deg) ? lsrc[nl*CAP + lane] : 0;

    uint4 v0, v1, v2, v3;
    PREF(v0, g) PREF(v1, 4+g) PREF(v2, 8+g) PREF(v3, 12+g)

    float x0 = 0.f, x1 = 0.f;
    if (lane < deg){
      float2 as = *(const float2*)&a_src[sreg*2];
      x0 = __expf(fminf(lrelu(as.x + ad.x), 60.f));
      x1 = __expf(fminf(lrelu(as.y + ad.y), 60.f));
    }
    float d0 = x0, d1 = x1;
    if (deg > 32){ d0 += __shfl_xor(d0,32,64); d1 += __shfl_xor(d1,32,64); }
    if (deg > 16){ d0 += __shfl_xor(d0,16,64); d1 += __shfl_xor(d1,16,64); }
    #pragma unroll
    for (int d = 8; d >= 1; d >>= 1){ d0 += __shfl_xor(d0,d,64); d1 += __shfl_xor(d1,d,64); }
    float inv0 = __builtin_amdgcn_rcpf(d0 + 1e-16f);
    float inv1 = __builtin_amdgcn_rcpf(d1 + 1e-16f);
    float al0 = x0 * inv0, al1 = x1 * inv1;

    f32x2 acc0 = {0.f,0.f}, acc1 = {0.f,0.f}, acc2 = {0.f,0.f}, acc3 = {0.f,0.f};
    int base = 0;
    for (;;){
      CONS(v0, base+g);
      if (base + 4 >= deg) break;
      CONS(v1, base+4+g);
      if (base + 8 >= deg) break;
      CONS(v2, base+8+g);
      if (base + 12 >= deg) break;
      CONS(v3, base+12+g);
      base += 16;
      if (base >= deg) break;
      PREF(v0, base+g) PREF(v1, base+4+g) PREF(v2, base+8+g) PREF(v3, base+12+g)
    }

    float acc[8] = {acc0.x, acc0.y, acc1.x, acc1.y, acc2.x, acc2.y, acc3.x, acc3.y};
    #pragma unroll
    for (int j = 0; j < 8; ++j){
      acc[j] += __shfl_xor(acc[j], 16, 64);
      acc[j] += __shfl_xor(acc[j], 32, 64);
    }

    float s = 0.f;
    if (g == 0 && actv){
      float4 b0 = *(const float4*)&bias_p[k*8];
      float4 b1 = *(const float4*)&bias_p[k*8 + 4];
      float4 f0 = *(const float4*)&fcwp[k*8];
      float4 f1 = *(const float4*)&fcwp[k*8 + 4];
      s  = fmaxf(acc[0]+b0.x, 0.f)*f0.x + fmaxf(acc[1]+b0.y, 0.f)*f0.y
         + fmaxf(acc[2]+b0.z, 0.f)*f0.z + fmaxf(acc[3]+b0.w, 0.f)*f0.w
         + fmaxf(acc[4]+b1.x, 0.f)*f1.x + fmaxf(acc[5]+b1.y, 0.f)*f1.y
         + fmaxf(acc[6]+b1.z, 0.f)*f1.z + fmaxf(acc[7]+b1.w, 0.f)*f1.w;
    }
    #pragma unroll
    for (int d = 1; d <= 8; d <<= 1) s += __shfl_xor(s, d, 64);
    if (lane == 0){
      int bb = xsb[n];
      atomicAdd(&ypart[(size_t)((bb*YSLOT + (b & (YSLOT-1))) << 5)], s);
    }
  }
#undef PREF
#undef CONS
}

// fold ypart (B x YSLOT line-padded) into y; y[b] already holds fcb.
// Kept as its own kernel: the boundary guarantees cross-XCD visibility.
__global__ __launch_bounds__(64) void k_red(const float* __restrict__ ypart,
    const float* __restrict__ invb, float* __restrict__ y)
{
  int b = blockIdx.x, t = threadIdx.x;
  float v = (t < YSLOT) ? ypart[(size_t)((b*YSLOT + t) << 5)] : 0.f;
  #pragma unroll
  for (int d = 16; d >= 1; d >>= 1) v += __shfl_xor(v, d, 64);
  if (t == 0) y[b] += v * invb[b];
}

extern "C" void kernel_launch(void* const* d_in, const int* in_sizes, int n_in,
                              void* d_out, int out_size, void* d_ws, size_t ws_size,
                              hipStream_t stream)
{
  const float* x_s  = (const float*)d_in[0];
  const float* x_t  = (const float*)d_in[1];
  const int*   ei   = (const int*)d_in[2];
  const int*   xsb  = (const int*)d_in[4];
  const float* Ws   = (const float*)d_in[6];
  const float* Wd   = (const float*)d_in[7];
  const float* atts = (const float*)d_in[8];
  const float* attd = (const float*)d_in[9];
  const float* bias = (const float*)d_in[10];
  const float* fcw  = (const float*)d_in[11];
  const float* fcb  = (const float*)d_in[12];
  float* y = (float*)d_out;

  const int N = in_sizes[4];   // 100000
  const int E = in_sizes[3];   // 1600000
  const int B = out_size;      // 64

  char* p = (char*)d_ws;
  auto carve = [&](size_t bytes)->char*{
    char* r = p; p += (bytes + 255) & ~(size_t)255; return r;
  };
  float*          wv     = (float*)         carve(256*4);
  float*          a_src  = (float*)         carve((size_t)N*2*4);
  float*          a_dst  = (float*)         carve((size_t)N*2*4);
  unsigned short* hsb    = (unsigned short*)carve((size_t)(N+64)*PW*2);
  float*          bias_p = (float*)         carve(128*4);
  float*          fcwp   = (float*)         carve(128*4);
  unsigned short* Wp     = (unsigned short*)carve((size_t)1792*8*2);
  float*          invb   = (float*)         carve(256*4);
  int*            bincnt = (int*)           carve(2048*4);
  float*          ypart  = (float*)         carve((size_t)B*YSLOT*32*4);
  int*            ebuf   = (int*)           carve((size_t)NBIN*BCAP*4);

  const int Gg = (N + 63) / 64;        // 1563 gemm blocks
  const int Gb = (E + ACH - 1) / ACH;  // 391 binA blocks (x256 rows = 100096 a_dst)

  k_init  <<<4, 256, 0, stream>>>(Wd, attd, Ws, bias, fcw, fcb, xsb,
                                  wv, bias_p, fcwp, Wp, invb, bincnt, ypart, y, N, B);
  k_fused <<<Gb + Gg, 256, 0, stream>>>(x_s, Wp, atts, hsb, a_src,
                                        x_t, wv, a_dst,
                                        ei, bincnt, ebuf, N, E, Gb);
  k_agg   <<<NBIN*2, 128, 0, stream>>>(bincnt, ebuf, a_src, a_dst, hsb,
                                       bias_p, fcwp, xsb, ypart, N);
  k_red   <<<B, 64, 0, stream>>>(ypart, invb, y);
}

// Round 8
// 270.766 us; speedup vs baseline: 1.0721x; 1.0721x over previous
//
#include <hip/hip_runtime.h>
#include <math.h>

#define D_IN 128
#define HC 100
#define PW 128          // padded hs row width (ushorts); rows 256B-aligned.
#define CAP 64          // per-dst bucket capacity; P(Poisson(16) > 64) ~ 1e-19
#define NEG 0.2f
#define BINSH 6         // bin = dst >> 6 (64 nodes/bin, 1563 bins for N=100000)
#define NBIN 1563
#define BCAP 1408       // per-bin edge capacity (avg 1024, +12 sigma)
#define ACH 4096        // edges per binA block
#define YSLOT 32        // ypart slots per batch; slot=blk&31 -> XCD-private lines
#define SRCM 0x1FFFF    // 17-bit src mask in packed ebuf entry

typedef __attribute__((ext_vector_type(8))) short short8;
typedef __attribute__((ext_vector_type(4))) float f32x4;
typedef __attribute__((ext_vector_type(2))) float f32x2;

__device__ __forceinline__ float lrelu(float x){ return x > 0.f ? x : NEG*x; }

__device__ __forceinline__ unsigned short f2bf(float f){
  union { float f; unsigned u; } v; v.f = f;
  unsigned r = v.u + 0x7fffu + ((v.u >> 16) & 1u);   // RNE
  return (unsigned short)(r >> 16);
}
__device__ __forceinline__ float bflo(unsigned u){
  union { unsigned x; float f; } v; v.x = u << 16; return v.f;
}
__device__ __forceinline__ float bfhi(unsigned u){
  union { unsigned x; float f; } v; v.x = u & 0xffff0000u; return v.f;
}

// block 0: wv = W_dst . att_dst; padded bias/fcw tables; y[b] = fcb; invb;
//          zero bincnt.  block 1: pack W_src into MFMA B-fragment order.
// blocks 2,3: zero ypart.
__global__ __launch_bounds__(256) void k_init(const float* __restrict__ Wd,
    const float* __restrict__ attd, const float* __restrict__ Ws,
    const float* __restrict__ bias, const float* __restrict__ fcw,
    const float* __restrict__ fcb, const int* __restrict__ xsb,
    float* __restrict__ wv, float* __restrict__ bias_p, float* __restrict__ fcwp,
    unsigned short* __restrict__ Wp, float* __restrict__ invb,
    int* __restrict__ bincnt, float* __restrict__ ypart,
    float* __restrict__ y, int N, int B){
  __shared__ int lo[257];
  int t = threadIdx.x;
  if (blockIdx.x == 0){
    int h = t >> 7, k = t & 127;
    float s = 0.f;
    #pragma unroll
    for (int c = 0; c < 50; ++c) s += Wd[k*HC + h*50 + c] * attd[h*50 + c];
    wv[t] = s;
    if (t < 128){
      bool cv = (t < 50) || (t >= 56 && t < 106);
      int c = (t < 50) ? t : t - 6;
      bias_p[t] = cv ? bias[c] : 0.f;
      fcwp[t]   = cv ? fcw[c]  : 0.f;
    }
    if (t < B) y[t] = fcb[0];
    for (int i = t; i < NBIN; i += 256) bincnt[i] = 0;
    if (t <= B && t < 257){
      int key = t, l = 0, hi = N;
      while (l < hi){ int mid = (l+hi)>>1; if (xsb[mid] < key) l = mid+1; else hi = mid; }
      lo[t] = l;
    }
    __syncthreads();
    if (t < B){
      int c = lo[t+1] - lo[t];
      invb[t] = 1.f / (float)((c > 0) ? c : 1);
    }
  } else if (blockIdx.x == 1){
    for (int idx = t; idx < 1792; idx += 256){
      int ct = idx >> 8, kk = (idx >> 6) & 3, lane = idx & 63;
      int kb = kk*32 + (lane >> 4)*8;
      int c  = ct*16 + (lane & 15);
      #pragma unroll
      for (int j = 0; j < 8; ++j){
        float v = (c < HC) ? Ws[(size_t)(kb + j)*HC + c] : 0.f;
        Wp[idx*8 + j] = f2bf(v);
      }
    }
  } else {
    // zero ypart: B*YSLOT*32 floats = 65536 -> 8192 float4 per block
    float4 z = make_float4(0.f,0.f,0.f,0.f);
    float4* yp4 = (float4*)ypart + (size_t)(blockIdx.x - 2)*8192;
    for (int i = t; i < 8192; i += 256) yp4[i] = z;
  }
}

// Grid-partitioned fused kernel: [0,Gb) binA FIRST (its global-atomic burst
// overlaps the gemm bulk instead of straggling at the end) | [Gb,..) gemm+adst.
__global__ __launch_bounds__(256) void k_fused(
    const float* __restrict__ x_s, const unsigned short* __restrict__ Wp,
    const float* __restrict__ atts, unsigned short* __restrict__ hsb,
    float* __restrict__ a_src,
    const float* __restrict__ x_t, const float* __restrict__ wv,
    float* __restrict__ a_dst,
    const int* __restrict__ ei, int* __restrict__ bincnt,
    int* __restrict__ ebuf,
    int N, int E, int Gb)
{
  __shared__ __align__(16) unsigned char smem[17408];
  int t = threadIdx.x;
  int bid = blockIdx.x;

  if (bid >= Gb){
    // ---- MFMA bf16 GEMM: hs = x_s @ W_src + fused a_src AND fp32 a_dst ----
    unsigned short* hls = (unsigned short*)smem;      // 64*PW ushorts = 16384 B
    float* wsh = (float*)(smem + 16384);              // 256 floats
    int lane = t & 63, w = t >> 6;
    int qr = lane & 15, qq = lane >> 4;
    int row0 = (bid - Gb)*64;

    wsh[t] = wv[t];
    for (int i = t; i < 4096; i += 256) ((unsigned*)hls)[i] = 0u;

    int arow = row0 + w*16 + qr;
    bool rv = arow < N;
    short8 afr[4];
    const float* xp  = x_s + (size_t)arow*D_IN + qq*8;
    const float* xtp = x_t + (size_t)arow*D_IN + qq*8;
    #pragma unroll
    for (int kk = 0; kk < 4; ++kk){
      float4 v0 = make_float4(0.f,0.f,0.f,0.f), v1 = v0;
      if (rv){ v0 = *(const float4*)(xp + kk*32); v1 = *(const float4*)(xp + kk*32 + 4); }
      short8 a;
      a[0]=(short)f2bf(v0.x); a[1]=(short)f2bf(v0.y); a[2]=(short)f2bf(v0.z); a[3]=(short)f2bf(v0.w);
      a[4]=(short)f2bf(v1.x); a[5]=(short)f2bf(v1.y); a[6]=(short)f2bf(v1.z); a[7]=(short)f2bf(v1.w);
      afr[kk] = a;
    }
    // x_t prefetch issued BEFORE the barrier: both row-load batches in flight.
    float4 u[8];
    #pragma unroll
    for (int kk = 0; kk < 4; ++kk){
      u[2*kk]   = rv ? *(const float4*)(xtp + kk*32)     : make_float4(0.f,0.f,0.f,0.f);
      u[2*kk+1] = rv ? *(const float4*)(xtp + kk*32 + 4) : make_float4(0.f,0.f,0.f,0.f);
    }

    __syncthreads();   // wsh staged; hls zero complete

    // a_dst for the same rows, fp32-exact.
    float pd0 = 0.f, pd1 = 0.f;
    #pragma unroll
    for (int kk = 0; kk < 4; ++kk){
      float4 u0 = u[2*kk], u1 = u[2*kk+1];
      int kb = qq*8 + kk*32;
      pd0 += u0.x*wsh[kb+0] + u0.y*wsh[kb+1] + u0.z*wsh[kb+2] + u0.w*wsh[kb+3]
           + u1.x*wsh[kb+4] + u1.y*wsh[kb+5] + u1.z*wsh[kb+6] + u1.w*wsh[kb+7];
      pd1 += u0.x*wsh[128+kb+0] + u0.y*wsh[128+kb+1] + u0.z*wsh[128+kb+2] + u0.w*wsh[128+kb+3]
           + u1.x*wsh[128+kb+4] + u1.y*wsh[128+kb+5] + u1.z*wsh[128+kb+6] + u1.w*wsh[128+kb+7];
    }
    pd0 += __shfl_xor(pd0, 16, 64); pd0 += __shfl_xor(pd0, 32, 64);
    pd1 += __shfl_xor(pd1, 16, 64); pd1 += __shfl_xor(pd1, 32, 64);
    if (qq == 0 && rv){ a_dst[arow*2] = pd0; a_dst[arow*2+1] = pd1; }

    f32x4 acc[7];
    #pragma unroll
    for (int ct = 0; ct < 7; ++ct) acc[ct] = (f32x4){0.f,0.f,0.f,0.f};
    #pragma unroll
    for (int kk = 0; kk < 4; ++kk){
      #pragma unroll
      for (int ct = 0; ct < 7; ++ct){
        short8 b = *(const short8*)&Wp[(size_t)((ct*4+kk)*64 + lane)*8];
        acc[ct] = __builtin_amdgcn_mfma_f32_16x16x32_bf16(afr[kk], b, acc[ct], 0, 0, 0);
      }
    }

    float p0[4] = {0,0,0,0}, p1[4] = {0,0,0,0};
    #pragma unroll
    for (int ct = 0; ct < 7; ++ct){
      int c = ct*16 + qr;
      if (c < HC){
        float av = atts[c];
        #pragma unroll
        for (int r = 0; r < 4; ++r){
          float v = acc[ct][r];
          if (c < 50) p0[r] += v*av; else p1[r] += v*av;
        }
      }
    }
    #pragma unroll
    for (int d = 1; d < 16; d <<= 1){
      #pragma unroll
      for (int r = 0; r < 4; ++r){
        p0[r] += __shfl_xor(p0[r], d, 64);
        p1[r] += __shfl_xor(p1[r], d, 64);
      }
    }
    if (qr == 0){
      #pragma unroll
      for (int r = 0; r < 4; ++r){
        int row = row0 + w*16 + qq*4 + r;
        if (row < N){ a_src[row*2] = p0[r]; a_src[row*2+1] = p1[r]; }
      }
    }

    #pragma unroll
    for (int ct = 0; ct < 7; ++ct){
      int c = ct*16 + qr;
      if (c < HC){
        int p = (c < 50) ? c : c + 6;
        #pragma unroll
        for (int r = 0; r < 4; ++r)
          hls[(w*16 + qq*4 + r)*PW + p] = f2bf(acc[ct][r]);
      }
    }
    __syncthreads();
    unsigned* hg = (unsigned*)(hsb + (size_t)row0*PW);
    for (int i = t; i < 4096; i += 256) hg[i] = ((unsigned*)hls)[i];

  } else {
    // ---- binA: bin edges by dst>>BINSH; LDS rank + one reserve-atomic/bin.
    //      Packed entry: src (17b) | local-dst (6b) << 17  -> int ebuf.
    int* cnt   = (int*)smem;          // [NBIN]
    int* gbase = (int*)smem + NBIN;   // [NBIN]  (2*1563*4 = 12504 B <= 17408)
    int e0 = bid * ACH;
    for (int i = t; i < NBIN; i += 256) cnt[i] = 0;
    __syncthreads();

    int src[16], dst[16], rank[16];
    #pragma unroll
    for (int j = 0; j < 4; ++j){
      int e = e0 + t*16 + j*4;
      bool in = (e + 4 <= E);                 // E % 4 == 0: chunks fully in or out
      int4 s4 = in ? *(const int4*)&ei[e]     : make_int4(0,0,0,0);
      int4 d4 = in ? *(const int4*)&ei[E + e] : make_int4(-1,-1,-1,-1);
      src[j*4+0]=s4.x; src[j*4+1]=s4.y; src[j*4+2]=s4.z; src[j*4+3]=s4.w;
      dst[j*4+0]=d4.x; dst[j*4+1]=d4.y; dst[j*4+2]=d4.z; dst[j*4+3]=d4.w;
    }
    #pragma unroll
    for (int j = 0; j < 16; ++j)
      rank[j] = (dst[j] >= 0) ? atomicAdd(&cnt[dst[j] >> BINSH], 1) : -1;
    __syncthreads();
    for (int i = t; i < NBIN; i += 256)
      gbase[i] = (cnt[i] > 0) ? atomicAdd(&bincnt[i], cnt[i]) : 0;
    __syncthreads();
    #pragma unroll
    for (int j = 0; j < 16; ++j){
      if (rank[j] >= 0){
        int b = dst[j] >> BINSH;
        int gp = gbase[b] + rank[j];
        if (gp < BCAP) ebuf[(size_t)b*BCAP + gp] = src[j] | ((dst[j] & 63) << 17);
      }
    }
  }
}

// Merged binB + agg: block b owns HALF-bin b (32 nodes, 128 threads).
// Phase 1 filters/groups the bin's packed edges into an LDS bucket table;
// phase 2: 2 waves x 16 nodes each run the per-node flow. Softmax WITHOUT
// max-subtraction: exp(e)/sum(exp(e)) is mathematically identical and logits
// are bounded (|e| <~ 20 for this model; clamp 60 guards overflow) -> removes
// the entire 14-op max butterfly chain per node.
__global__ __launch_bounds__(128) void k_agg(const int* __restrict__ bincnt,
    const int* __restrict__ ebuf, const float* __restrict__ a_src,
    const float* __restrict__ a_dst, const unsigned short* __restrict__ hsb,
    const float* __restrict__ bias_p, const float* __restrict__ fcwp,
    const int* __restrict__ xsb, float* __restrict__ ypart, int N)
{
  __shared__ int lsrc[32*CAP];    // 8192 B
  __shared__ int lcnt[32];
  int t = threadIdx.x, b = blockIdx.x;
  int bin = b >> 1, half = b & 1;
  if (t < 32) lcnt[t] = 0;
  __syncthreads();
  int nE = bincnt[bin]; if (nE > BCAP) nE = BCAP;
  const int* eb = ebuf + (size_t)bin*BCAP;
  for (int i = t; i < nE; i += 128){
    int e = eb[i];
    int ld = (e >> 17) & 63;
    if ((ld >> 5) == half){
      int p = atomicAdd(&lcnt[ld & 31], 1);
      if (p < CAP) lsrc[(ld & 31)*CAP + p] = e & SRCM;
    }
  }
  __syncthreads();

  int lane = t & 63, w = t >> 6;
  int k = lane & 15, g = lane >> 4;
  bool actv = (k < 14);
  bool hsel = (k >= 7);

#define PREF(vv, e) { int s_ = __shfl(sreg, (e), 64); \
    vv = (actv && (e) < deg) ? *(const uint4*)&hsb[(size_t)s_*PW + k*8] \
                             : make_uint4(0u,0u,0u,0u); }

#define CONS(vv, e) { float a0_ = __shfl(al0, (e), 64); float a1_ = __shfl(al1, (e), 64); \
    float a_ = hsel ? a1_ : a0_; f32x2 av_ = {a_, a_}; \
    f32x2 h0_ = {bflo(vv.x), bfhi(vv.x)}; acc0 += av_*h0_; \
    f32x2 h1_ = {bflo(vv.y), bfhi(vv.y)}; acc1 += av_*h1_; \
    f32x2 h2_ = {bflo(vv.z), bfhi(vv.z)}; acc2 += av_*h2_; \
    f32x2 h3_ = {bflo(vv.w), bfhi(vv.w)}; acc3 += av_*h3_; }

  for (int it = 0; it < 16; ++it){
    int nl = w*16 + it;
    int n  = bin*64 + half*32 + nl;
    if (n >= N) break;                 // wave-uniform; no barriers below
    int deg = lcnt[nl]; if (deg > CAP) deg = CAP;
    float2 ad = *(const float2*)&a_dst[n*2];
    int sreg = (lane < deg) ? lsrc[nl*CAP + lane] : 0;

    uint4 v0, v1, v2, v3;
    PREF(v0, g) PREF(v1, 4+g) PREF(v2, 8+g) PREF(v3, 12+g)

    float x0 = 0.f, x1 = 0.f;
    if (lane < deg){
      float2 as = *(const float2*)&a_src[sreg*2];
      x0 = __expf(fminf(lrelu(as.x + ad.x), 60.f));
      x1 = __expf(fminf(lrelu(as.y + ad.y), 60.f));
    }
    float d0 = x0, d1 = x1;
    if (deg > 32){ d0 += __shfl_xor(d0,32,64); d1 += __shfl_xor(d1,32,64); }
    if (deg > 16){ d0 += __shfl_xor(d0,16,64); d1 += __shfl_xor(d1,16,64); }
    #pragma unroll
    for (int d = 8; d >= 1; d >>= 1){ d0 += __shfl_xor(d0,d,64); d1 += __shfl_xor(d1,d,64); }
    float inv0 = __builtin_amdgcn_rcpf(d0 + 1e-16f);
    float inv1 = __builtin_amdgcn_rcpf(d1 + 1e-16f);
    float al0 = x0 * inv0, al1 = x1 * inv1;

    f32x2 acc0 = {0.f,0.f}, acc1 = {0.f,0.f}, acc2 = {0.f,0.f}, acc3 = {0.f,0.f};
    int base = 0;
    for (;;){
      CONS(v0, base+g);
      if (base + 4 >= deg) break;
      CONS(v1, base+4+g);
      if (base + 8 >= deg) break;
      CONS(v2, base+8+g);
      if (base + 12 >= deg) break;
      CONS(v3, base+12+g);
      base += 16;
      if (base >= deg) break;
      PREF(v0, base+g) PREF(v1, base+4+g) PREF(v2, base+8+g) PREF(v3, base+12+g)
    }

    float acc[8] = {acc0.x, acc0.y, acc1.x, acc1.y, acc2.x, acc2.y, acc3.x, acc3.y};
    #pragma unroll
    for (int j = 0; j < 8; ++j){
      acc[j] += __shfl_xor(acc[j], 16, 64);
      acc[j] += __shfl_xor(acc[j], 32, 64);
    }

    float s = 0.f;
    if (g == 0 && actv){
      float4 b0 = *(const float4*)&bias_p[k*8];
      float4 b1 = *(const float4*)&bias_p[k*8 + 4];
      float4 f0 = *(const float4*)&fcwp[k*8];
      float4 f1 = *(const float4*)&fcwp[k*8 + 4];
      s  = fmaxf(acc[0]+b0.x, 0.f)*f0.x + fmaxf(acc[1]+b0.y, 0.f)*f0.y
         + fmaxf(acc[2]+b0.z, 0.f)*f0.z + fmaxf(acc[3]+b0.w, 0.f)*f0.w
         + fmaxf(acc[4]+b1.x, 0.f)*f1.x + fmaxf(acc[5]+b1.y, 0.f)*f1.y
         + fmaxf(acc[6]+b1.z, 0.f)*f1.z + fmaxf(acc[7]+b1.w, 0.f)*f1.w;
    }
    #pragma unroll
    for (int d = 1; d <= 8; d <<= 1) s += __shfl_xor(s, d, 64);
    if (lane == 0){
      int bb = xsb[n];
      atomicAdd(&ypart[(size_t)((bb*YSLOT + (b & (YSLOT-1))) << 5)], s);
    }
  }
#undef PREF
#undef CONS
}

// fold ypart (B x YSLOT line-padded) into y; y[b] already holds fcb.
// Kept as its own kernel: the boundary guarantees cross-XCD visibility.
__global__ __launch_bounds__(64) void k_red(const float* __restrict__ ypart,
    const float* __restrict__ invb, float* __restrict__ y)
{
  int b = blockIdx.x, t = threadIdx.x;
  float v = (t < YSLOT) ? ypart[(size_t)((b*YSLOT + t) << 5)] : 0.f;
  #pragma unroll
  for (int d = 16; d >= 1; d >>= 1) v += __shfl_xor(v, d, 64);
  if (t == 0) y[b] += v * invb[b];
}

extern "C" void kernel_launch(void* const* d_in, const int* in_sizes, int n_in,
                              void* d_out, int out_size, void* d_ws, size_t ws_size,
                              hipStream_t stream)
{
  const float* x_s  = (const float*)d_in[0];
  const float* x_t  = (const float*)d_in[1];
  const int*   ei   = (const int*)d_in[2];
  const int*   xsb  = (const int*)d_in[4];
  const float* Ws   = (const float*)d_in[6];
  const float* Wd   = (const float*)d_in[7];
  const float* atts = (const float*)d_in[8];
  const float* attd = (const float*)d_in[9];
  const float* bias = (const float*)d_in[10];
  const float* fcw  = (const float*)d_in[11];
  const float* fcb  = (const float*)d_in[12];
  float* y = (float*)d_out;

  const int N = in_sizes[4];   // 100000
  const int E = in_sizes[3];   // 1600000
  const int B = out_size;      // 64

  char* p = (char*)d_ws;
  auto carve = [&](size_t bytes)->char*{
    char* r = p; p += (bytes + 255) & ~(size_t)255; return r;
  };
  float*          wv     = (float*)         carve(256*4);
  float*          a_src  = (float*)         carve((size_t)N*2*4);
  float*          a_dst  = (float*)         carve((size_t)N*2*4);
  unsigned short* hsb    = (unsigned short*)carve((size_t)(N+64)*PW*2);
  float*          bias_p = (float*)         carve(128*4);
  float*          fcwp   = (float*)         carve(128*4);
  unsigned short* Wp     = (unsigned short*)carve((size_t)1792*8*2);
  float*          invb   = (float*)         carve(256*4);
  int*            bincnt = (int*)           carve(2048*4);
  float*          ypart  = (float*)         carve((size_t)B*YSLOT*32*4);
  int*            ebuf   = (int*)           carve((size_t)NBIN*BCAP*4);

  const int Gg = (N + 63) / 64;        // 1563 gemm blocks
  const int Gb = (E + ACH - 1) / ACH;  // 391 binA blocks

  k_init  <<<4, 256, 0, stream>>>(Wd, attd, Ws, bias, fcw, fcb, xsb,
                                  wv, bias_p, fcwp, Wp, invb, bincnt, ypart, y, N, B);
  k_fused <<<Gb + Gg, 256, 0, stream>>>(x_s, Wp, atts, hsb, a_src,
                                        x_t, wv, a_dst,
                                        ei, bincnt, ebuf, N, E, Gb);
  k_agg   <<<NBIN*2, 128, 0, stream>>>(bincnt, ebuf, a_src, a_dst, hsb,
                                       bias_p, fcwp, xsb, ypart, N);
  k_red   <<<B, 64, 0, stream>>>(ypart, invb, y);
}

// Round 10
// 262.047 us; speedup vs baseline: 1.1077x; 1.0333x over previous
//
#include <hip/hip_runtime.h>
#include <math.h>

#define D_IN 128
#define HC 100
#define PW 128          // padded hs row width (ushorts); rows 256B-aligned.
#define CAP 64          // per-dst bucket capacity; P(Poisson(16) > 64) ~ 1e-19
#define NEG 0.2f
#define BINSH 6         // bin = dst >> 6 (64 nodes/bin, 1563 bins for N=100000)
#define NBIN 1563
#define BCAP 1408       // per-bin edge capacity (avg 1024, +12 sigma)
#define ACH 4096        // edges per binA block
#define YSLOT 32        // ypart slots per batch; slot=blk&31 -> XCD-private lines
#define SRCM 0x1FFFF    // 17-bit src mask in packed ebuf entry

typedef __attribute__((ext_vector_type(8))) short short8;
typedef __attribute__((ext_vector_type(4))) float f32x4;
typedef __attribute__((ext_vector_type(2))) float f32x2;

__device__ __forceinline__ float lrelu(float x){ return x > 0.f ? x : NEG*x; }

__device__ __forceinline__ unsigned short f2bf(float f){
  union { float f; unsigned u; } v; v.f = f;
  unsigned r = v.u + 0x7fffu + ((v.u >> 16) & 1u);   // RNE
  return (unsigned short)(r >> 16);
}
__device__ __forceinline__ float bflo(unsigned u){
  union { unsigned x; float f; } v; v.x = u << 16; return v.f;
}
__device__ __forceinline__ float bfhi(unsigned u){
  union { unsigned x; float f; } v; v.x = u & 0xffff0000u; return v.f;
}

// block 0: wv = W_dst . att_dst; padded bias/fcw tables; y[b] = fcb; invb;
//          zero bincnt.  blocks 1..7: pack one ct-tile of W_src each into
//          MFMA B-fragment order.  blocks 8..11: zero ypart quarter each.
__global__ __launch_bounds__(256) void k_init(const float* __restrict__ Wd,
    const float* __restrict__ attd, const float* __restrict__ Ws,
    const float* __restrict__ bias, const float* __restrict__ fcw,
    const float* __restrict__ fcb, const int* __restrict__ xsb,
    float* __restrict__ wv, float* __restrict__ bias_p, float* __restrict__ fcwp,
    unsigned short* __restrict__ Wp, float* __restrict__ invb,
    int* __restrict__ bincnt, float* __restrict__ ypart,
    float* __restrict__ y, int N, int B){
  __shared__ int lo[257];
  int t = threadIdx.x;
  if (blockIdx.x == 0){
    int h = t >> 7, k = t & 127;
    float s = 0.f;
    #pragma unroll
    for (int c = 0; c < 50; ++c) s += Wd[k*HC + h*50 + c] * attd[h*50 + c];
    wv[t] = s;
    if (t < 128){
      bool cv = (t < 50) || (t >= 56 && t < 106);
      int c = (t < 50) ? t : t - 6;
      bias_p[t] = cv ? bias[c] : 0.f;
      fcwp[t]   = cv ? fcw[c]  : 0.f;
    }
    if (t < B) y[t] = fcb[0];
    for (int i = t; i < NBIN; i += 256) bincnt[i] = 0;
    if (t <= B && t < 257){
      int key = t, l = 0, hi = N;
      while (l < hi){ int mid = (l+hi)>>1; if (xsb[mid] < key) l = mid+1; else hi = mid; }
      lo[t] = l;
    }
    __syncthreads();
    if (t < B){
      int c = lo[t+1] - lo[t];
      invb[t] = 1.f / (float)((c > 0) ? c : 1);
    }
  } else if (blockIdx.x < 8){
    // one ct-tile per block: idx = ct*256 + t
    int ct = blockIdx.x - 1;
    int idx = ct*256 + t;
    int kk = (t >> 6) & 3, lane = t & 63;
    int kb = kk*32 + (lane >> 4)*8;
    int c  = ct*16 + (lane & 15);
    #pragma unroll
    for (int j = 0; j < 8; ++j){
      float v = (c < HC) ? Ws[(size_t)(kb + j)*HC + c] : 0.f;
      Wp[idx*8 + j] = f2bf(v);
    }
  } else {
    // zero ypart: B*YSLOT*32 floats = 16384 float4 over 4 blocks
    float4 z = make_float4(0.f,0.f,0.f,0.f);
    float4* yp4 = (float4*)ypart + (size_t)(blockIdx.x - 8)*4096;
    for (int i = t; i < 4096; i += 256) yp4[i] = z;
  }
}

// Grid-partitioned fused kernel: [0,Gb) binA FIRST (its global-atomic burst
// overlaps the gemm bulk) | [Gb,..) gemm+adst.
// Gemm branch is phase-ordered so x_t regs (u[8]) die before afr/acc live:
// peak VGPR ~60 -> 8 waves/SIMD for latency hiding (was 88 -> 5 waves).
__global__ __launch_bounds__(256) void k_fused(
    const float* __restrict__ x_s, const unsigned short* __restrict__ Wp,
    const float* __restrict__ atts, unsigned short* __restrict__ hsb,
    float* __restrict__ a_src,
    const float* __restrict__ x_t, const float* __restrict__ wv,
    float* __restrict__ a_dst,
    const int* __restrict__ ei, int* __restrict__ bincnt,
    int* __restrict__ ebuf,
    int N, int E, int Gb)
{
  __shared__ __align__(16) unsigned char smem[17408];
  int t = threadIdx.x;
  int bid = blockIdx.x;

  if (bid >= Gb){
    // ---- phase order: issue x_t loads | LDS housekeeping | barrier |
    //      a_dst (u dies) | afr loads | MFMA | epilogues ----
    unsigned short* hls = (unsigned short*)smem;      // 64*PW ushorts = 16384 B
    float* wsh = (float*)(smem + 16384);              // 256 floats
    int lane = t & 63, w = t >> 6;
    int qr = lane & 15, qq = lane >> 4;
    int row0 = (bid - Gb)*64;

    int arow = row0 + w*16 + qr;
    bool rv = arow < N;

    // x_t loads issued first; they fly during housekeeping + barrier.
    const float* xtp = x_t + (size_t)arow*D_IN + qq*8;
    float4 u[8];
    #pragma unroll
    for (int kk = 0; kk < 4; ++kk){
      u[2*kk]   = rv ? *(const float4*)(xtp + kk*32)     : make_float4(0.f,0.f,0.f,0.f);
      u[2*kk+1] = rv ? *(const float4*)(xtp + kk*32 + 4) : make_float4(0.f,0.f,0.f,0.f);
    }

    wsh[t] = wv[t];
    for (int i = t; i < 4096; i += 256) ((unsigned*)hls)[i] = 0u;
    __syncthreads();   // wsh staged; hls zero complete

    // a_dst, fp32-exact; u[] dies here.
    float pd0 = 0.f, pd1 = 0.f;
    #pragma unroll
    for (int kk = 0; kk < 4; ++kk){
      float4 u0 = u[2*kk], u1 = u[2*kk+1];
      int kb = qq*8 + kk*32;
      pd0 += u0.x*wsh[kb+0] + u0.y*wsh[kb+1] + u0.z*wsh[kb+2] + u0.w*wsh[kb+3]
           + u1.x*wsh[kb+4] + u1.y*wsh[kb+5] + u1.z*wsh[kb+6] + u1.w*wsh[kb+7];
      pd1 += u0.x*wsh[128+kb+0] + u0.y*wsh[128+kb+1] + u0.z*wsh[128+kb+2] + u0.w*wsh[128+kb+3]
           + u1.x*wsh[128+kb+4] + u1.y*wsh[128+kb+5] + u1.z*wsh[128+kb+6] + u1.w*wsh[128+kb+7];
    }
    pd0 += __shfl_xor(pd0, 16, 64); pd0 += __shfl_xor(pd0, 32, 64);
    pd1 += __shfl_xor(pd1, 16, 64); pd1 += __shfl_xor(pd1, 32, 64);
    if (qq == 0 && rv){ a_dst[arow*2] = pd0; a_dst[arow*2+1] = pd1; }

    // x_s -> bf16 A-fragments (u regs now free)
    short8 afr[4];
    const float* xp = x_s + (size_t)arow*D_IN + qq*8;
    #pragma unroll
    for (int kk = 0; kk < 4; ++kk){
      float4 v0 = make_float4(0.f,0.f,0.f,0.f), v1 = v0;
      if (rv){ v0 = *(const float4*)(xp + kk*32); v1 = *(const float4*)(xp + kk*32 + 4); }
      short8 a;
      a[0]=(short)f2bf(v0.x); a[1]=(short)f2bf(v0.y); a[2]=(short)f2bf(v0.z); a[3]=(short)f2bf(v0.w);
      a[4]=(short)f2bf(v1.x); a[5]=(short)f2bf(v1.y); a[6]=(short)f2bf(v1.z); a[7]=(short)f2bf(v1.w);
      afr[kk] = a;
    }

    f32x4 acc[7];
    #pragma unroll
    for (int ct = 0; ct < 7; ++ct) acc[ct] = (f32x4){0.f,0.f,0.f,0.f};
    #pragma unroll
    for (int kk = 0; kk < 4; ++kk){
      #pragma unroll
      for (int ct = 0; ct < 7; ++ct){
        short8 b = *(const short8*)&Wp[(size_t)((ct*4+kk)*64 + lane)*8];
        acc[ct] = __builtin_amdgcn_mfma_f32_16x16x32_bf16(afr[kk], b, acc[ct], 0, 0, 0);
      }
    }

    float p0[4] = {0,0,0,0}, p1[4] = {0,0,0,0};
    #pragma unroll
    for (int ct = 0; ct < 7; ++ct){
      int c = ct*16 + qr;
      if (c < HC){
        float av = atts[c];
        #pragma unroll
        for (int r = 0; r < 4; ++r){
          float v = acc[ct][r];
          if (c < 50) p0[r] += v*av; else p1[r] += v*av;
        }
      }
    }
    #pragma unroll
    for (int d = 1; d < 16; d <<= 1){
      #pragma unroll
      for (int r = 0; r < 4; ++r){
        p0[r] += __shfl_xor(p0[r], d, 64);
        p1[r] += __shfl_xor(p1[r], d, 64);
      }
    }
    if (qr == 0){
      #pragma unroll
      for (int r = 0; r < 4; ++r){
        int row = row0 + w*16 + qq*4 + r;
        if (row < N){ a_src[row*2] = p0[r]; a_src[row*2+1] = p1[r]; }
      }
    }

    #pragma unroll
    for (int ct = 0; ct < 7; ++ct){
      int c = ct*16 + qr;
      if (c < HC){
        int p = (c < 50) ? c : c + 6;
        #pragma unroll
        for (int r = 0; r < 4; ++r)
          hls[(w*16 + qq*4 + r)*PW + p] = f2bf(acc[ct][r]);
      }
    }
    __syncthreads();
    unsigned* hg = (unsigned*)(hsb + (size_t)row0*PW);
    for (int i = t; i < 4096; i += 256) hg[i] = ((unsigned*)hls)[i];

  } else {
    // ---- binA: bin edges by dst>>BINSH; LDS rank + one reserve-atomic/bin.
    //      Packed entry: src (17b) | local-dst (6b) << 17  -> int ebuf.
    int* cnt   = (int*)smem;          // [NBIN]
    int* gbase = (int*)smem + NBIN;   // [NBIN]  (2*1563*4 = 12504 B <= 17408)
    int e0 = bid * ACH;
    for (int i = t; i < NBIN; i += 256) cnt[i] = 0;
    __syncthreads();

    int src[16], dst[16], rank[16];
    #pragma unroll
    for (int j = 0; j < 4; ++j){
      int e = e0 + t*16 + j*4;
      bool in = (e + 4 <= E);                 // E % 4 == 0: chunks fully in or out
      int4 s4 = in ? *(const int4*)&ei[e]     : make_int4(0,0,0,0);
      int4 d4 = in ? *(const int4*)&ei[E + e] : make_int4(-1,-1,-1,-1);
      src[j*4+0]=s4.x; src[j*4+1]=s4.y; src[j*4+2]=s4.z; src[j*4+3]=s4.w;
      dst[j*4+0]=d4.x; dst[j*4+1]=d4.y; dst[j*4+2]=d4.z; dst[j*4+3]=d4.w;
    }
    #pragma unroll
    for (int j = 0; j < 16; ++j)
      rank[j] = (dst[j] >= 0) ? atomicAdd(&cnt[dst[j] >> BINSH], 1) : -1;
    __syncthreads();
    for (int i = t; i < NBIN; i += 256)
      gbase[i] = (cnt[i] > 0) ? atomicAdd(&bincnt[i], cnt[i]) : 0;
    __syncthreads();
    #pragma unroll
    for (int j = 0; j < 16; ++j){
      if (rank[j] >= 0){
        int b = dst[j] >> BINSH;
        int gp = gbase[b] + rank[j];
        if (gp < BCAP) ebuf[(size_t)b*BCAP + gp] = src[j] | ((dst[j] & 63) << 17);
      }
    }
  }
}

// Merged binB + agg: block b owns HALF-bin b (32 nodes, 128 threads).
// Phase 1 filters/groups the bin's packed edges into an LDS bucket table;
// phase 2: 2 waves x 16 nodes each run the per-node flow. Softmax WITHOUT
// max-subtraction (exact up to fp32 assoc.; clamp 60 guards overflow).
__global__ __launch_bounds__(128) void k_agg(const int* __restrict__ bincnt,
    const int* __restrict__ ebuf, const float* __restrict__ a_src,
    const float* __restrict__ a_dst, const unsigned short* __restrict__ hsb,
    const float* __restrict__ bias_p, const float* __restrict__ fcwp,
    const int* __restrict__ xsb, float* __restrict__ ypart, int N)
{
  __shared__ int lsrc[32*CAP];    // 8192 B
  __shared__ int lcnt[32];
  int t = threadIdx.x, b = blockIdx.x;
  int bin = b >> 1, half = b & 1;
  if (t < 32) lcnt[t] = 0;
  __syncthreads();
  int nE = bincnt[bin]; if (nE > BCAP) nE = BCAP;
  const int* eb = ebuf + (size_t)bin*BCAP;
  for (int i = t; i < nE; i += 128){
    int e = eb[i];
    int ld = (e >> 17) & 63;
    if ((ld >> 5) == half){
      int p = atomicAdd(&lcnt[ld & 31], 1);
      if (p < CAP) lsrc[(ld & 31)*CAP + p] = e & SRCM;
    }
  }
  __syncthreads();

  int lane = t & 63, w = t >> 6;
  int k = lane & 15, g = lane >> 4;
  bool actv = (k < 14);
  bool hsel = (k >= 7);

#define PREF(vv, e) { int s_ = __shfl(sreg, (e), 64); \
    vv = (actv && (e) < deg) ? *(const uint4*)&hsb[(size_t)s_*PW + k*8] \
                             : make_uint4(0u,0u,0u,0u); }

#define CONS(vv, e) { float a0_ = __shfl(al0, (e), 64); float a1_ = __shfl(al1, (e), 64); \
    float a_ = hsel ? a1_ : a0_; f32x2 av_ = {a_, a_}; \
    f32x2 h0_ = {bflo(vv.x), bfhi(vv.x)}; acc0 += av_*h0_; \
    f32x2 h1_ = {bflo(vv.y), bfhi(vv.y)}; acc1 += av_*h1_; \
    f32x2 h2_ = {bflo(vv.z), bfhi(vv.z)}; acc2 += av_*h2_; \
    f32x2 h3_ = {bflo(vv.w), bfhi(vv.w)}; acc3 += av_*h3_; }

  for (int it = 0; it < 16; ++it){
    int nl = w*16 + it;
    int n  = bin*64 + half*32 + nl;
    if (n >= N) break;                 // wave-uniform; no barriers below
    int deg = lcnt[nl]; if (deg > CAP) deg = CAP;
    float2 ad = *(const float2*)&a_dst[n*2];
    int sreg = (lane < deg) ? lsrc[nl*CAP + lane] : 0;

    uint4 v0, v1, v2, v3;
    PREF(v0, g) PREF(v1, 4+g) PREF(v2, 8+g) PREF(v3, 12+g)

    float x0 = 0.f, x1 = 0.f;
    if (lane < deg){
      float2 as = *(const float2*)&a_src[sreg*2];
      x0 = __expf(fminf(lrelu(as.x + ad.x), 60.f));
      x1 = __expf(fminf(lrelu(as.y + ad.y), 60.f));
    }
    float d0 = x0, d1 = x1;
    if (deg > 32){ d0 += __shfl_xor(d0,32,64); d1 += __shfl_xor(d1,32,64); }
    if (deg > 16){ d0 += __shfl_xor(d0,16,64); d1 += __shfl_xor(d1,16,64); }
    #pragma unroll
    for (int d = 8; d >= 1; d >>= 1){ d0 += __shfl_xor(d0,d,64); d1 += __shfl_xor(d1,d,64); }
    float inv0 = __builtin_amdgcn_rcpf(d0 + 1e-16f);
    float inv1 = __builtin_amdgcn_rcpf(d1 + 1e-16f);
    float al0 = x0 * inv0, al1 = x1 * inv1;

    f32x2 acc0 = {0.f,0.f}, acc1 = {0.f,0.f}, acc2 = {0.f,0.f}, acc3 = {0.f,0.f};
    int base = 0;
    for (;;){
      CONS(v0, base+g);
      if (base + 4 >= deg) break;
      CONS(v1, base+4+g);
      if (base + 8 >= deg) break;
      CONS(v2, base+8+g);
      if (base + 12 >= deg) break;
      CONS(v3, base+12+g);
      base += 16;
      if (base >= deg) break;
      PREF(v0, base+g) PREF(v1, base+4+g) PREF(v2, base+8+g) PREF(v3, base+12+g)
    }

    float acc[8] = {acc0.x, acc0.y, acc1.x, acc1.y, acc2.x, acc2.y, acc3.x, acc3.y};
    #pragma unroll
    for (int j = 0; j < 8; ++j){
      acc[j] += __shfl_xor(acc[j], 16, 64);
      acc[j] += __shfl_xor(acc[j], 32, 64);
    }

    float s = 0.f;
    if (g == 0 && actv){
      float4 b0 = *(const float4*)&bias_p[k*8];
      float4 b1 = *(const float4*)&bias_p[k*8 + 4];
      float4 f0 = *(const float4*)&fcwp[k*8];
      float4 f1 = *(const float4*)&fcwp[k*8 + 4];
      s  = fmaxf(acc[0]+b0.x, 0.f)*f0.x + fmaxf(acc[1]+b0.y, 0.f)*f0.y
         + fmaxf(acc[2]+b0.z, 0.f)*f0.z + fmaxf(acc[3]+b0.w, 0.f)*f0.w
         + fmaxf(acc[4]+b1.x, 0.f)*f1.x + fmaxf(acc[5]+b1.y, 0.f)*f1.y
         + fmaxf(acc[6]+b1.z, 0.f)*f1.z + fmaxf(acc[7]+b1.w, 0.f)*f1.w;
    }
    #pragma unroll
    for (int d = 1; d <= 8; d <<= 1) s += __shfl_xor(s, d, 64);
    if (lane == 0){
      int bb = xsb[n];
      atomicAdd(&ypart[(size_t)((bb*YSLOT + (b & (YSLOT-1))) << 5)], s);
    }
  }
#undef PREF
#undef CONS
}

// fold ypart (B x YSLOT line-padded) into y; y[b] already holds fcb.
// Kept as its own kernel: the boundary guarantees cross-XCD visibility.
__global__ __launch_bounds__(64) void k_red(const float* __restrict__ ypart,
    const float* __restrict__ invb, float* __restrict__ y)
{
  int b = blockIdx.x, t = threadIdx.x;
  float v = (t < YSLOT) ? ypart[(size_t)((b*YSLOT + t) << 5)] : 0.f;
  #pragma unroll
  for (int d = 16; d >= 1; d >>= 1) v += __shfl_xor(v, d, 64);
  if (t == 0) y[b] += v * invb[b];
}

extern "C" void kernel_launch(void* const* d_in, const int* in_sizes, int n_in,
                              void* d_out, int out_size, void* d_ws, size_t ws_size,
                              hipStream_t stream)
{
  const float* x_s  = (const float*)d_in[0];
  const float* x_t  = (const float*)d_in[1];
  const int*   ei   = (const int*)d_in[2];
  const int*   xsb  = (const int*)d_in[4];
  const float* Ws   = (const float*)d_in[6];
  const float* Wd   = (const float*)d_in[7];
  const float* atts = (const float*)d_in[8];
  const float* attd = (const float*)d_in[9];
  const float* bias = (const float*)d_in[10];
  const float* fcw  = (const float*)d_in[11];
  const float* fcb  = (const float*)d_in[12];
  float* y = (float*)d_out;

  const int N = in_sizes[4];   // 100000
  const int E = in_sizes[3];   // 1600000
  const int B = out_size;      // 64

  char* p = (char*)d_ws;
  auto carve = [&](size_t bytes)->char*{
    char* r = p; p += (bytes + 255) & ~(size_t)255; return r;
  };
  float*          wv     = (float*)         carve(256*4);
  float*          a_src  = (float*)         carve((size_t)N*2*4);
  float*          a_dst  = (float*)         carve((size_t)N*2*4);
  unsigned short* hsb    = (unsigned short*)carve((size_t)(N+64)*PW*2);
  float*          bias_p = (float*)         carve(128*4);
  float*          fcwp   = (float*)         carve(128*4);
  unsigned short* Wp     = (unsigned short*)carve((size_t)1792*8*2);
  float*          invb   = (float*)         carve(256*4);
  int*            bincnt = (int*)           carve(2048*4);
  float*          ypart  = (float*)         carve((size_t)B*YSLOT*32*4);
  int*            ebuf   = (int*)           carve((size_t)NBIN*BCAP*4);

  const int Gg = (N + 63) / 64;        // 1563 gemm blocks
  const int Gb = (E + ACH - 1) / ACH;  // 391 binA blocks

  k_init  <<<12, 256, 0, stream>>>(Wd, attd, Ws, bias, fcw, fcb, xsb,
                                   wv, bias_p, fcwp, Wp, invb, bincnt, ypart, y, N, B);
  k_fused <<<Gb + Gg, 256, 0, stream>>>(x_s, Wp, atts, hsb, a_src,
                                        x_t, wv, a_dst,
                                        ei, bincnt, ebuf, N, E, Gb);
  k_agg   <<<NBIN*2, 128, 0, stream>>>(bincnt, ebuf, a_src, a_dst, hsb,
                                       bias_p, fcwp, xsb, ypart, N);
  k_red   <<<B, 64, 0, stream>>>(ypart, invb, y);
}